// Round 13
// baseline (191.951 us; speedup 1.0000x reference)
//
#include <hip/hip_runtime.h>

namespace {

typedef float v4f __attribute__((ext_vector_type(4)));
typedef _Float16 half4 __attribute__((ext_vector_type(4)));
typedef __fp16 fp16x2 __attribute__((ext_vector_type(2)));
typedef unsigned int uint32;

constexpr int   kB     = 32768;
constexpr int   kT     = 50;
constexpr float kDT    = 0.01f;
constexpr float kGamma = 0.1f;
constexpr float kSigma = 0.2f;
constexpr float kTau   = 0.5f;
constexpr float kA     = 2.8853900817779268f;   // 2*log2(e)

// 17 MFMA A-fragments (v_mfma_f32_16x16x16_f16; lane holds A[m][k], m=lane&15,
// k=(lane>>4)*4+j). ACTIVATION-FOLDED: act(v)=rcp(exp2(v)+1); tanh=1-2r folded
// into next layer (W'=-2W, b'=b+sumW); act-feeding layers pre-scaled by kA.
// 0 y0L1  1 y0L2  2 y0L3  3 L1z(x)  4 L1p(x)  5 L2z  6 L2p  7 L3z  8 L3p
// 9 Arow  11 Crow  13 Acol  15 Bcol
// L3-FOLDED drift composites (consume act(g) directly; b3-folded form):
// 10 BWP = -2*Bm*pW3'   12 DWP = -2*Dm*pW3'
// 14 CWZ = -2*Cm^T*zW3' 16 DWZ = -2*Dm^T*zW3'
constexpr int kNFrag      = 17;
constexpr int kFragDwords = kNFrag * 128;
// bias arrays (16 f32 each):
// 0 cy1 1 cy2 2 cy3 3 c2z 4 c2p 5 c3z 6 c3p 7 vtz 8 vbz 9 vtp 10 vbp
// 11 bpb=Bm*b3p' 12 dpb=Dm*b3p' 13 czb=Cm^T*b3z' 14 dzb=Dm^T*b3z'
constexpr int kBiasFloats = 15 * 16;

__device__ __forceinline__ float fexp2(float x) {
#if __has_builtin(__builtin_amdgcn_exp2f)
  return __builtin_amdgcn_exp2f(x);
#else
  return exp2f(x);
#endif
}

__device__ __forceinline__ float fact(float x) {   // rcp(exp2(x)+1)
  return __builtin_amdgcn_rcpf(fexp2(x) + 1.0f);
}

__device__ __forceinline__ v4f act4(v4f a) {
  v4f r;
  r[0] = fact(a[0]); r[1] = fact(a[1]);
  r[2] = fact(a[2]); r[3] = fact(a[3]);
  return r;
}

__device__ __forceinline__ uint32 pk2rtn(float a, float b) {  // round-nearest
  union { _Float16 h[2]; uint32 u; } z;
  z.h[0] = (_Float16)a; z.h[1] = (_Float16)b;
  return z.u;
}

// ---------------- prep: 18 blocks, one fragment (or bias set) each ---------
__global__ __launch_bounds__(64) void prep_kernel(
    const float* __restrict__ A,   const float* __restrict__ Bm,
    const float* __restrict__ Cm,  const float* __restrict__ Dm,
    const float* __restrict__ pW1, const float* __restrict__ pb1,
    const float* __restrict__ pW2, const float* __restrict__ pb2,
    const float* __restrict__ pW3, const float* __restrict__ pb3,
    const float* __restrict__ zW1, const float* __restrict__ zb1,
    const float* __restrict__ zW2, const float* __restrict__ zb2,
    const float* __restrict__ zW3, const float* __restrict__ zb3,
    const float* __restrict__ yW1, const float* __restrict__ yb1,
    const float* __restrict__ yW2, const float* __restrict__ yb2,
    const float* __restrict__ yW3, const float* __restrict__ yb3,
    uint32* __restrict__ ws)
{
  const int tid = threadIdx.x;
  const int blk = blockIdx.x;

  auto sum10 = [](const float* W, int stride, int mm) {
    float s = 0.f;
#pragma unroll
    for (int j = 0; j < 10; ++j) s += W[j * stride + mm];
    return s;
  };

  if (blk < kNFrag) {
    const int m = tid & 15, q = tid >> 4;
    const int p = blk;

    auto wv = [&](int k) -> float {
      float s = 0.f;
      switch (p) {
        case 0:  return (m < 10) ? kA * yW1[k * 10 + m] : 0.f;
        case 1:  return (m < 10 && k < 10) ? -2.f * kA * yW2[k * 10 + m] : 0.f;
        case 2:  return (k < 10) ? -2.f * yW3[k * 16 + m] : 0.f;
        case 3:  return (m < 10) ? kA * zW1[(k + 1) * 10 + m] : 0.f;
        case 4:  return (m < 10) ? kA * pW1[(k + 1) * 10 + m] : 0.f;
        case 5:  return (m < 10 && k < 10) ? -2.f * kA * zW2[k * 10 + m] : 0.f;
        case 6:  return (m < 10 && k < 10) ? -2.f * kA * pW2[k * 10 + m] : 0.f;
        case 7:  return (k < 10) ? -2.f * zW3[k * 16 + m] : 0.f;
        case 8:  return (m < 8 && k < 10) ? -2.f * pW3[k * 8 + m] : 0.f;
        case 9:  return A[m * 16 + k];                      // dx: x @ A^T
        case 11: return Cm[m * 16 + k];                     // fx: x @ C^T
        case 13: return A[k * 16 + m];                      // dy: Y @ A
        case 15: return (m < 8) ? Bm[k * 8 + m] : 0.f;      // dh: Y @ B
        case 10:                                            // BWP[m][j]
          if (k >= 10) return 0.f;
#pragma unroll
          for (int qq = 0; qq < 8; ++qq) s += Bm[m * 8 + qq] * pW3[k * 8 + qq];
          return -2.f * s;
        case 12:                                            // DWP[m][j]
          if (k >= 10) return 0.f;
#pragma unroll
          for (int qq = 0; qq < 8; ++qq) s += Dm[m * 8 + qq] * pW3[k * 8 + qq];
          return -2.f * s;
        case 14:                                            // CWZ[m][j]
          if (k >= 10) return 0.f;
#pragma unroll
          for (int kk = 0; kk < 16; ++kk) s += zW3[k * 16 + kk] * Cm[kk * 16 + m];
          return -2.f * s;
        case 16:                                            // DWZ[m][j]
          if (m >= 8 || k >= 10) return 0.f;
#pragma unroll
          for (int kk = 0; kk < 16; ++kk) s += zW3[k * 16 + kk] * Dm[kk * 8 + m];
          return -2.f * s;
      }
      return 0.f;
    };

    const int k0 = 4 * q;
    ws[p * 128 + tid * 2]     = pk2rtn(wv(k0),     wv(k0 + 1));
    ws[p * 128 + tid * 2 + 1] = pk2rtn(wv(k0 + 2), wv(k0 + 3));
  } else {
    float* bsf = (float*)(ws + kFragDwords);
    // folded L3 biases: b3p'_q = pb3[q]+sum_j pW3[j][q]; b3z'_k = zb3[k]+sum_j zW3[j][k]
    auto b3p = [&](int q) { return pb3[q] + sum10(pW3, 8, q); };
    auto b3z = [&](int k) { return zb3[k] + sum10(zW3, 16, k); };
    auto bval = [&](int a, int mm) -> float {
      const bool m10 = mm < 10;
      float s = 0.f;
      switch (a) {
        case 0:  return m10 ? kA * yb1[mm] : 0.f;
        case 1:  return m10 ? kA * (yb2[mm] + sum10(yW2, 10, mm)) : 0.f;
        case 2:  return yb3[mm] + sum10(yW3, 16, mm);
        case 3:  return m10 ? kA * (zb2[mm] + sum10(zW2, 10, mm)) : 0.f;
        case 4:  return m10 ? kA * (pb2[mm] + sum10(pW2, 10, mm)) : 0.f;
        case 5:  return b3z(mm);
        case 6:  return (mm < 8) ? b3p(mm) : 0.f;
        case 7:  return m10 ? kA * zW1[mm] : 0.f;   // zW1 row 0 = t-row
        case 8:  return m10 ? kA * zb1[mm] : 0.f;
        case 9:  return m10 ? kA * pW1[mm] : 0.f;
        case 10: return m10 ? kA * pb1[mm] : 0.f;
        case 11:                                    // bpb[m] = sum_q Bm[m][q] b3p'_q
#pragma unroll
          for (int q = 0; q < 8; ++q) s += Bm[mm * 8 + q] * b3p(q);
          return s;
        case 12:                                    // dpb[m]
#pragma unroll
          for (int q = 0; q < 8; ++q) s += Dm[mm * 8 + q] * b3p(q);
          return s;
        case 13:                                    // czb[m] = sum_k Cm[k][m] b3z'_k
#pragma unroll
          for (int k = 0; k < 16; ++k) s += Cm[k * 16 + mm] * b3z(k);
          return s;
        case 14:                                    // dzb[m]
          if (mm >= 8) return 0.f;
#pragma unroll
          for (int k = 0; k < 16; ++k) s += Dm[k * 8 + mm] * b3z(k);
          return s;
      }
      return 0.f;
    };
    for (int j = tid; j < kBiasFloats; j += 64) {
      bsf[j] = bval(j >> 4, j & 15);
    }
  }
}

// --- main: 2-wave skewed pipeline. wave1 = X/phi (interval i = step i),
// --- wave0 = Y/Z (interval i = step i-1). L3 folded out of both recurrences.
// --- T5: setprio(1) around each wave's compute body (2 independent blocks
// --- per SIMD at different phases -> scheduler has something to arbitrate).
__global__ __launch_bounds__(128)
__attribute__((amdgpu_waves_per_eu(2, 4)))
void bsde_kernel(const float* __restrict__ dw, const float* __restrict__ X0,
                 const uint32* __restrict__ wsu, float* __restrict__ out)
{
  const int tid  = threadIdx.x;
  const int w    = tid >> 6;          // 0: Y/Z-wave, 1: X/phi-wave
  const int lane = tid & 63;
  const int col  = lane & 15;
  const int quad = lane >> 4;
  const int e    = blockIdx.x * 16 + col;
  const int bq   = quad * 4;

  __shared__ float sx[2][64][4];      // x(s+1) produced in interval s
  __shared__ float su[2][64][4];      // u(s)   produced in interval s

  auto ldfrag = [&](int p) -> half4 {
    union { uint2 u; half4 h; } z;
    z.u = *(const uint2*)(wsu + p * 128 + lane * 2);
    return z.h;
  };
  const float* bsf = (const float*)(wsu + kFragDwords);

  // Per-wave fragments (wave-uniform selection).
  const half4 aL1 = ldfrag(w ? 4 : 3);     // L1p / L1z
  const half4 aL2 = ldfrag(w ? 6 : 5);     // L2p / L2z
  const half4 aL3 = ldfrag(w ? 8 : 7);     // L3p(u) / L3z(z) — off-path
  const half4 aE1 = ldfrag(w ? 9 : 13);    // Arow / Acol
  const half4 aE2 = ldfrag(w ? 11 : 15);   // Crow / Bcol
  const half4 aW1 = ldfrag(w ? 10 : 14);   // BWP  / CWZ
  const half4 aW2 = ldfrag(w ? 12 : 16);   // DWP  / DWZ
  const v4f c2 = *(const v4f*)&bsf[(w ? 4 : 3) * 16 + bq];
  const v4f c3 = *(const v4f*)&bsf[(w ? 6 : 5) * 16 + bq];
  const v4f vt = *(const v4f*)&bsf[(w ? 9 : 7) * 16 + bq];
  const v4f vb = *(const v4f*)&bsf[(w ? 10 : 8) * 16 + bq];
  v4f s1c, s2c;
  {
    const v4f ba = *(const v4f*)&bsf[(w ? 11 : 13) * 16 + bq];
    const v4f bb = *(const v4f*)&bsf[(w ? 12 : 14) * 16 + bq];
#pragma unroll
    for (int r = 0; r < 4; ++r) {
      s1c[r] = w ? (kGamma + ba[r]) : ba[r];   // gamma+bpb | czb
      s2c[r] = w ? (kSigma + bb[r]) : bb[r];   // sigma+dpb | dzb
    }
  }

  auto pk4 = [](v4f a) -> half4 {
    union { fp16x2 p[2]; half4 h; } z;
    z.p[0] = __builtin_amdgcn_cvt_pkrtz(a[0], a[1]);
    z.p[1] = __builtin_amdgcn_cvt_pkrtz(a[2], a[3]);
    return z.h;
  };
  auto mm4 = [](half4 a, half4 b, v4f c) -> v4f {
    return __builtin_amdgcn_mfma_f32_16x16x16f16(a, b, c, 0, 0, 0);
  };

  // ---- init ----
  v4f x4 = *(const v4f*)&X0[e * 16 + bq];   // wave1: x(i); wave0: x(s)
  half4 xB = pk4(x4);
  v4f y4 = {0.f, 0.f, 0.f, 0.f};
  half4 yB = pk4(y4);
  if (w == 0) {   // Y0 MLP (transient fragments)
    const half4 a0 = ldfrag(0), a1 = ldfrag(1), a2 = ldfrag(2);
    const v4f cy1 = *(const v4f*)&bsf[0 * 16 + bq];
    const v4f cy2 = *(const v4f*)&bsf[1 * 16 + bq];
    const v4f cy3 = *(const v4f*)&bsf[2 * 16 + bq];
    v4f h = mm4(a0, xB, cy1);
    v4f g = mm4(a1, pk4(act4(h)), cy2);
    y4    = mm4(a2, pk4(act4(g)), cy3);
    yB    = pk4(y4);
  }

  float dwc = dw[e];        // wave1: dw[i] at interval i; wave0: dw[i-1]
  float lcp = 0.0f;

  // -------------------------- skewed time loop ----------------------------
#pragma unroll 1
  for (int i = 0; i <= kT; ++i) {
    const int idx = w ? (i + 1) : i;
    const float dwn = (idx < kT) ? dw[idx * kB + e] : 0.0f;

    if (w) {
      if (i < kT) {
        __builtin_amdgcn_s_setprio(1);
        const float tv = (float)i * kDT;
        v4f c1;
#pragma unroll
        for (int r = 0; r < 4; ++r) c1[r] = vb[r] + tv * vt[r];
        v4f h = mm4(aL1, xB, c1);
        half4 hB = pk4(act4(h));
        v4f g = mm4(aL2, hB, c2);
        half4 gB = pk4(act4(g));
        v4f u = mm4(aL3, gB, c3);               // export only (off-path)
        *(v4f*)&su[i & 1][lane][0] = u;
        v4f s1 = mm4(aE1, xB, s1c);             // x@A^T + gamma + bpb
        v4f s2 = mm4(aE2, xB, s2c);             // x@C^T + sigma + dpb
        v4f dx = mm4(aW1, gB, s1);              // + BWP*act(g) = +u@B^T
        v4f fx = mm4(aW2, gB, s2);              // + DWP*act(g) = +u@D^T
        v4f Xn;
#pragma unroll
        for (int r = 0; r < 4; ++r) Xn[r] = x4[r] + kDT * dx[r] + dwc * fx[r];
        *(v4f*)&sx[i & 1][lane][0] = Xn;
        x4 = Xn;
        xB = pk4(x4);
        __builtin_amdgcn_s_setprio(0);
      }
    } else {
      if (i >= 1) {
        __builtin_amdgcn_s_setprio(1);
        const int s = i - 1;
        const float tv = (float)s * kDT;
        const float wt = (s == 0 || s == kT - 1) ? 1.0f : 2.0f;
        v4f c1;
#pragma unroll
        for (int r = 0; r < 4; ++r) c1[r] = vb[r] + tv * vt[r];
        v4f h = mm4(aL1, xB, c1);               // xB = pk(x(s))
        half4 hB = pk4(act4(h));
        v4f g = mm4(aL2, hB, c2);
        half4 gB = pk4(act4(g));
        v4f zv = mm4(aL3, gB, c3);              // z(s) (for Yn only)
        v4f s1yc;
#pragma unroll
        for (int r = 0; r < 4; ++r) s1yc[r] = x4[r] + s1c[r];  // X + czb
        v4f s1y = mm4(aE1, yB, s1yc);           // Y@A + X + czb
        v4f s2y = mm4(aE2, yB, s2c);            // Y@B + dzb
        v4f dy = mm4(aW1, gB, s1y);             // + CWZ*act = +Z@C
        v4f dh = mm4(aW2, gB, s2y);             // + DWZ*act = +Z@D
        const v4f uu = *(const v4f*)&su[s & 1][lane][0];
        v4f Yn;
        float ss = 0.0f;
#pragma unroll
        for (int r = 0; r < 4; ++r) {
          Yn[r] = y4[r] - kDT * dy[r] + dwc * zv[r];
          float d = dh[r] + uu[r];
          ss += d * d;
        }
        lcp += (0.5f * kDT * kTau * kTau) * wt * ss;
        y4 = Yn;
        yB = pk4(y4);
        x4 = *(const v4f*)&sx[s & 1][lane][0];   // x(s+1), full interval slack
        xB = pk4(x4);
        __builtin_amdgcn_s_setprio(0);
      }
    }
    __syncthreads();
    dwc = dwn;
  }

  // ---- losses (wave0 only; no barriers below) ----
  if (w == 0) {
    float bp = 0.0f;
#pragma unroll
    for (int r = 0; r < 4; ++r) { float d = y4[r] - x4[r]; bp += d * d; }
#pragma unroll
    for (int s = 32; s > 0; s >>= 1) {
      bp  += __shfl_down(bp,  s, 64);
      lcp += __shfl_down(lcp, s, 64);
    }
    if (lane == 0) {
      atomicAdd(&out[0], bp  * (1.0f / (float)kB));
      atomicAdd(&out[1], lcp * (1.0f / (float)kB));
    }
  }
}

} // namespace

extern "C" void kernel_launch(void* const* d_in, const int* in_sizes, int n_in,
                              void* d_out, int out_size, void* d_ws, size_t ws_size,
                              hipStream_t stream) {
  (void)in_sizes; (void)n_in; (void)ws_size; (void)out_size;

  const float* dw  = (const float*)d_in[0];
  const float* X0  = (const float*)d_in[1];
  const float* A   = (const float*)d_in[2];
  const float* Bm  = (const float*)d_in[3];
  const float* Cm  = (const float*)d_in[4];
  const float* Dm  = (const float*)d_in[5];
  const float* pW1 = (const float*)d_in[6];
  const float* pb1 = (const float*)d_in[7];
  const float* pW2 = (const float*)d_in[8];
  const float* pb2 = (const float*)d_in[9];
  const float* pW3 = (const float*)d_in[10];
  const float* pb3 = (const float*)d_in[11];
  const float* zW1 = (const float*)d_in[12];
  const float* zb1 = (const float*)d_in[13];
  const float* zW2 = (const float*)d_in[14];
  const float* zb2 = (const float*)d_in[15];
  const float* zW3 = (const float*)d_in[16];
  const float* zb3 = (const float*)d_in[17];
  const float* yW1 = (const float*)d_in[18];
  const float* yb1 = (const float*)d_in[19];
  const float* yW2 = (const float*)d_in[20];
  const float* yb2 = (const float*)d_in[21];
  const float* yW3 = (const float*)d_in[22];
  const float* yb3 = (const float*)d_in[23];
  float* out = (float*)d_out;
  unsigned int* ws = (unsigned int*)d_ws;

  (void)hipMemsetAsync(out, 0, 2 * sizeof(float), stream);

  prep_kernel<<<kNFrag + 1, 64, 0, stream>>>(
      A, Bm, Cm, Dm,
      pW1, pb1, pW2, pb2, pW3, pb3,
      zW1, zb1, zW2, zb2, zW3, zb3,
      yW1, yb1, yW2, yb2, yW3, yb3, ws);

  bsde_kernel<<<kB / 16, 128, 0, stream>>>(dw, X0, ws, out);
}

// Round 14
// 184.988 us; speedup vs baseline: 1.0376x; 1.0376x over previous
//
#include <hip/hip_runtime.h>

namespace {

typedef float v4f __attribute__((ext_vector_type(4)));
typedef _Float16 half4 __attribute__((ext_vector_type(4)));
typedef __fp16 fp16x2 __attribute__((ext_vector_type(2)));
typedef unsigned int uint32;

constexpr int   kB     = 32768;
constexpr int   kT     = 50;
constexpr float kDT    = 0.01f;
constexpr float kGamma = 0.1f;
constexpr float kSigma = 0.2f;
constexpr float kTau   = 0.5f;
constexpr float kA     = 2.8853900817779268f;   // 2*log2(e)

// 17 MFMA A-fragments (v_mfma_f32_16x16x16_f16; lane holds A[m][k], m=lane&15,
// k=(lane>>4)*4+j). ACTIVATION-FOLDED: act(v)=rcp(exp2(v)+1); tanh=1-2r folded
// into next layer (W'=-2W, b'=b+sumW); act-feeding layers pre-scaled by kA.
// 0 y0L1  1 y0L2  2 y0L3  3 L1z(x)  4 L1p(x)  5 L2z  6 L2p  7 L3z  8 L3p
// 9 Arow  11 Crow  13 Acol  15 Bcol
// L3-FOLDED drift composites (consume act(g) directly; b3-folded form):
// 10 BWP = -2*Bm*pW3'   12 DWP = -2*Dm*pW3'
// 14 CWZ = -2*Cm^T*zW3' 16 DWZ = -2*Dm^T*zW3'
constexpr int kNFrag      = 17;
constexpr int kFragDwords = kNFrag * 128;
// bias arrays (16 f32 each):
// 0 cy1 1 cy2 2 cy3 3 c2z 4 c2p 5 c3z 6 c3p 7 vtz 8 vbz 9 vtp 10 vbp
// 11 bpb=Bm*b3p' 12 dpb=Dm*b3p' 13 czb=Cm^T*b3z' 14 dzb=Dm^T*b3z'
constexpr int kBiasFloats = 15 * 16;

__device__ __forceinline__ float fexp2(float x) {
#if __has_builtin(__builtin_amdgcn_exp2f)
  return __builtin_amdgcn_exp2f(x);
#else
  return exp2f(x);
#endif
}

__device__ __forceinline__ float fact(float x) {   // rcp(exp2(x)+1)
  return __builtin_amdgcn_rcpf(fexp2(x) + 1.0f);
}

__device__ __forceinline__ v4f act4(v4f a) {
  v4f r;
  r[0] = fact(a[0]); r[1] = fact(a[1]);
  r[2] = fact(a[2]); r[3] = fact(a[3]);
  return r;
}

__device__ __forceinline__ uint32 pk2rtn(float a, float b) {  // round-nearest
  union { _Float16 h[2]; uint32 u; } z;
  z.h[0] = (_Float16)a; z.h[1] = (_Float16)b;
  return z.u;
}

// ---------------- prep: 18 blocks, one fragment (or bias set) each ---------
__global__ __launch_bounds__(64) void prep_kernel(
    const float* __restrict__ A,   const float* __restrict__ Bm,
    const float* __restrict__ Cm,  const float* __restrict__ Dm,
    const float* __restrict__ pW1, const float* __restrict__ pb1,
    const float* __restrict__ pW2, const float* __restrict__ pb2,
    const float* __restrict__ pW3, const float* __restrict__ pb3,
    const float* __restrict__ zW1, const float* __restrict__ zb1,
    const float* __restrict__ zW2, const float* __restrict__ zb2,
    const float* __restrict__ zW3, const float* __restrict__ zb3,
    const float* __restrict__ yW1, const float* __restrict__ yb1,
    const float* __restrict__ yW2, const float* __restrict__ yb2,
    const float* __restrict__ yW3, const float* __restrict__ yb3,
    uint32* __restrict__ ws)
{
  const int tid = threadIdx.x;
  const int blk = blockIdx.x;

  auto sum10 = [](const float* W, int stride, int mm) {
    float s = 0.f;
#pragma unroll
    for (int j = 0; j < 10; ++j) s += W[j * stride + mm];
    return s;
  };

  if (blk < kNFrag) {
    const int m = tid & 15, q = tid >> 4;
    const int p = blk;

    auto wv = [&](int k) -> float {
      float s = 0.f;
      switch (p) {
        case 0:  return (m < 10) ? kA * yW1[k * 10 + m] : 0.f;
        case 1:  return (m < 10 && k < 10) ? -2.f * kA * yW2[k * 10 + m] : 0.f;
        case 2:  return (k < 10) ? -2.f * yW3[k * 16 + m] : 0.f;
        case 3:  return (m < 10) ? kA * zW1[(k + 1) * 10 + m] : 0.f;
        case 4:  return (m < 10) ? kA * pW1[(k + 1) * 10 + m] : 0.f;
        case 5:  return (m < 10 && k < 10) ? -2.f * kA * zW2[k * 10 + m] : 0.f;
        case 6:  return (m < 10 && k < 10) ? -2.f * kA * pW2[k * 10 + m] : 0.f;
        case 7:  return (k < 10) ? -2.f * zW3[k * 16 + m] : 0.f;
        case 8:  return (m < 8 && k < 10) ? -2.f * pW3[k * 8 + m] : 0.f;
        case 9:  return A[m * 16 + k];                      // dx: x @ A^T
        case 11: return Cm[m * 16 + k];                     // fx: x @ C^T
        case 13: return A[k * 16 + m];                      // dy: Y @ A
        case 15: return (m < 8) ? Bm[k * 8 + m] : 0.f;      // dh: Y @ B
        case 10:                                            // BWP[m][j]
          if (k >= 10) return 0.f;
#pragma unroll
          for (int qq = 0; qq < 8; ++qq) s += Bm[m * 8 + qq] * pW3[k * 8 + qq];
          return -2.f * s;
        case 12:                                            // DWP[m][j]
          if (k >= 10) return 0.f;
#pragma unroll
          for (int qq = 0; qq < 8; ++qq) s += Dm[m * 8 + qq] * pW3[k * 8 + qq];
          return -2.f * s;
        case 14:                                            // CWZ[m][j]
          if (k >= 10) return 0.f;
#pragma unroll
          for (int kk = 0; kk < 16; ++kk) s += zW3[k * 16 + kk] * Cm[kk * 16 + m];
          return -2.f * s;
        case 16:                                            // DWZ[m][j]
          if (m >= 8 || k >= 10) return 0.f;
#pragma unroll
          for (int kk = 0; kk < 16; ++kk) s += zW3[k * 16 + kk] * Dm[kk * 8 + m];
          return -2.f * s;
      }
      return 0.f;
    };

    const int k0 = 4 * q;
    ws[p * 128 + tid * 2]     = pk2rtn(wv(k0),     wv(k0 + 1));
    ws[p * 128 + tid * 2 + 1] = pk2rtn(wv(k0 + 2), wv(k0 + 3));
  } else {
    float* bsf = (float*)(ws + kFragDwords);
    // folded L3 biases: b3p'_q = pb3[q]+sum_j pW3[j][q]; b3z'_k = zb3[k]+sum_j zW3[j][k]
    auto b3p = [&](int q) { return pb3[q] + sum10(pW3, 8, q); };
    auto b3z = [&](int k) { return zb3[k] + sum10(zW3, 16, k); };
    auto bval = [&](int a, int mm) -> float {
      const bool m10 = mm < 10;
      float s = 0.f;
      switch (a) {
        case 0:  return m10 ? kA * yb1[mm] : 0.f;
        case 1:  return m10 ? kA * (yb2[mm] + sum10(yW2, 10, mm)) : 0.f;
        case 2:  return yb3[mm] + sum10(yW3, 16, mm);
        case 3:  return m10 ? kA * (zb2[mm] + sum10(zW2, 10, mm)) : 0.f;
        case 4:  return m10 ? kA * (pb2[mm] + sum10(pW2, 10, mm)) : 0.f;
        case 5:  return b3z(mm);
        case 6:  return (mm < 8) ? b3p(mm) : 0.f;
        case 7:  return m10 ? kA * zW1[mm] : 0.f;   // zW1 row 0 = t-row
        case 8:  return m10 ? kA * zb1[mm] : 0.f;
        case 9:  return m10 ? kA * pW1[mm] : 0.f;
        case 10: return m10 ? kA * pb1[mm] : 0.f;
        case 11:                                    // bpb[m] = sum_q Bm[m][q] b3p'_q
#pragma unroll
          for (int q = 0; q < 8; ++q) s += Bm[mm * 8 + q] * b3p(q);
          return s;
        case 12:                                    // dpb[m]
#pragma unroll
          for (int q = 0; q < 8; ++q) s += Dm[mm * 8 + q] * b3p(q);
          return s;
        case 13:                                    // czb[m] = sum_k Cm[k][m] b3z'_k
#pragma unroll
          for (int k = 0; k < 16; ++k) s += Cm[k * 16 + mm] * b3z(k);
          return s;
        case 14:                                    // dzb[m]
          if (mm >= 8) return 0.f;
#pragma unroll
          for (int k = 0; k < 16; ++k) s += Dm[k * 8 + mm] * b3z(k);
          return s;
      }
      return 0.f;
    };
    for (int j = tid; j < kBiasFloats; j += 64) {
      bsf[j] = bval(j >> 4, j & 15);
    }
  }
}

// --- main: 2-wave skewed pipeline. wave1 = X/phi (interval i = step i),
// --- wave0 = Y/Z (interval i = step i-1). L3 folded out of both recurrences.
// --- Session optimum (measured twice: 78.7 and 79.3-81.3 us). No setprio:
// --- r13 showed setprio -6% here (barrier-coupled waves starve each other).
__global__ __launch_bounds__(128)
__attribute__((amdgpu_waves_per_eu(2, 4)))
void bsde_kernel(const float* __restrict__ dw, const float* __restrict__ X0,
                 const uint32* __restrict__ wsu, float* __restrict__ out)
{
  const int tid  = threadIdx.x;
  const int w    = tid >> 6;          // 0: Y/Z-wave, 1: X/phi-wave
  const int lane = tid & 63;
  const int col  = lane & 15;
  const int quad = lane >> 4;
  const int e    = blockIdx.x * 16 + col;
  const int bq   = quad * 4;

  __shared__ float sx[2][64][4];      // x(s+1) produced in interval s
  __shared__ float su[2][64][4];      // u(s)   produced in interval s

  auto ldfrag = [&](int p) -> half4 {
    union { uint2 u; half4 h; } z;
    z.u = *(const uint2*)(wsu + p * 128 + lane * 2);
    return z.h;
  };
  const float* bsf = (const float*)(wsu + kFragDwords);

  // Per-wave fragments (wave-uniform selection).
  const half4 aL1 = ldfrag(w ? 4 : 3);     // L1p / L1z
  const half4 aL2 = ldfrag(w ? 6 : 5);     // L2p / L2z
  const half4 aL3 = ldfrag(w ? 8 : 7);     // L3p(u) / L3z(z) — off-path
  const half4 aE1 = ldfrag(w ? 9 : 13);    // Arow / Acol
  const half4 aE2 = ldfrag(w ? 11 : 15);   // Crow / Bcol
  const half4 aW1 = ldfrag(w ? 10 : 14);   // BWP  / CWZ
  const half4 aW2 = ldfrag(w ? 12 : 16);   // DWP  / DWZ
  const v4f c2 = *(const v4f*)&bsf[(w ? 4 : 3) * 16 + bq];
  const v4f c3 = *(const v4f*)&bsf[(w ? 6 : 5) * 16 + bq];
  const v4f vt = *(const v4f*)&bsf[(w ? 9 : 7) * 16 + bq];
  const v4f vb = *(const v4f*)&bsf[(w ? 10 : 8) * 16 + bq];
  v4f s1c, s2c;
  {
    const v4f ba = *(const v4f*)&bsf[(w ? 11 : 13) * 16 + bq];
    const v4f bb = *(const v4f*)&bsf[(w ? 12 : 14) * 16 + bq];
#pragma unroll
    for (int r = 0; r < 4; ++r) {
      s1c[r] = w ? (kGamma + ba[r]) : ba[r];   // gamma+bpb | czb
      s2c[r] = w ? (kSigma + bb[r]) : bb[r];   // sigma+dpb | dzb
    }
  }

  auto pk4 = [](v4f a) -> half4 {
    union { fp16x2 p[2]; half4 h; } z;
    z.p[0] = __builtin_amdgcn_cvt_pkrtz(a[0], a[1]);
    z.p[1] = __builtin_amdgcn_cvt_pkrtz(a[2], a[3]);
    return z.h;
  };
  auto mm4 = [](half4 a, half4 b, v4f c) -> v4f {
    return __builtin_amdgcn_mfma_f32_16x16x16f16(a, b, c, 0, 0, 0);
  };

  // ---- init ----
  v4f x4 = *(const v4f*)&X0[e * 16 + bq];   // wave1: x(i); wave0: x(s)
  half4 xB = pk4(x4);
  v4f y4 = {0.f, 0.f, 0.f, 0.f};
  half4 yB = pk4(y4);
  if (w == 0) {   // Y0 MLP (transient fragments)
    const half4 a0 = ldfrag(0), a1 = ldfrag(1), a2 = ldfrag(2);
    const v4f cy1 = *(const v4f*)&bsf[0 * 16 + bq];
    const v4f cy2 = *(const v4f*)&bsf[1 * 16 + bq];
    const v4f cy3 = *(const v4f*)&bsf[2 * 16 + bq];
    v4f h = mm4(a0, xB, cy1);
    v4f g = mm4(a1, pk4(act4(h)), cy2);
    y4    = mm4(a2, pk4(act4(g)), cy3);
    yB    = pk4(y4);
  }

  float dwc = dw[e];        // wave1: dw[i] at interval i; wave0: dw[i-1]
  float lcp = 0.0f;

  // -------------------------- skewed time loop ----------------------------
#pragma unroll 1
  for (int i = 0; i <= kT; ++i) {
    const int idx = w ? (i + 1) : i;
    const float dwn = (idx < kT) ? dw[idx * kB + e] : 0.0f;

    if (w) {
      if (i < kT) {
        const float tv = (float)i * kDT;
        v4f c1;
#pragma unroll
        for (int r = 0; r < 4; ++r) c1[r] = vb[r] + tv * vt[r];
        v4f h = mm4(aL1, xB, c1);
        half4 hB = pk4(act4(h));
        v4f g = mm4(aL2, hB, c2);
        half4 gB = pk4(act4(g));
        v4f u = mm4(aL3, gB, c3);               // export only (off-path)
        *(v4f*)&su[i & 1][lane][0] = u;
        v4f s1 = mm4(aE1, xB, s1c);             // x@A^T + gamma + bpb
        v4f s2 = mm4(aE2, xB, s2c);             // x@C^T + sigma + dpb
        v4f dx = mm4(aW1, gB, s1);              // + BWP*act(g) = +u@B^T
        v4f fx = mm4(aW2, gB, s2);              // + DWP*act(g) = +u@D^T
        v4f Xn;
#pragma unroll
        for (int r = 0; r < 4; ++r) Xn[r] = x4[r] + kDT * dx[r] + dwc * fx[r];
        *(v4f*)&sx[i & 1][lane][0] = Xn;
        x4 = Xn;
        xB = pk4(x4);
      }
    } else {
      if (i >= 1) {
        const int s = i - 1;
        const float tv = (float)s * kDT;
        const float wt = (s == 0 || s == kT - 1) ? 1.0f : 2.0f;
        v4f c1;
#pragma unroll
        for (int r = 0; r < 4; ++r) c1[r] = vb[r] + tv * vt[r];
        v4f h = mm4(aL1, xB, c1);               // xB = pk(x(s))
        half4 hB = pk4(act4(h));
        v4f g = mm4(aL2, hB, c2);
        half4 gB = pk4(act4(g));
        v4f zv = mm4(aL3, gB, c3);              // z(s) (for Yn only)
        v4f s1yc;
#pragma unroll
        for (int r = 0; r < 4; ++r) s1yc[r] = x4[r] + s1c[r];  // X + czb
        v4f s1y = mm4(aE1, yB, s1yc);           // Y@A + X + czb
        v4f s2y = mm4(aE2, yB, s2c);            // Y@B + dzb
        v4f dy = mm4(aW1, gB, s1y);             // + CWZ*act = +Z@C
        v4f dh = mm4(aW2, gB, s2y);             // + DWZ*act = +Z@D
        const v4f uu = *(const v4f*)&su[s & 1][lane][0];
        v4f Yn;
        float ss = 0.0f;
#pragma unroll
        for (int r = 0; r < 4; ++r) {
          Yn[r] = y4[r] - kDT * dy[r] + dwc * zv[r];
          float d = dh[r] + uu[r];
          ss += d * d;
        }
        lcp += (0.5f * kDT * kTau * kTau) * wt * ss;
        y4 = Yn;
        yB = pk4(y4);
        x4 = *(const v4f*)&sx[s & 1][lane][0];   // x(s+1), full interval slack
        xB = pk4(x4);
      }
    }
    __syncthreads();
    dwc = dwn;
  }

  // ---- losses (wave0 only; no barriers below) ----
  if (w == 0) {
    float bp = 0.0f;
#pragma unroll
    for (int r = 0; r < 4; ++r) { float d = y4[r] - x4[r]; bp += d * d; }
#pragma unroll
    for (int s = 32; s > 0; s >>= 1) {
      bp  += __shfl_down(bp,  s, 64);
      lcp += __shfl_down(lcp, s, 64);
    }
    if (lane == 0) {
      atomicAdd(&out[0], bp  * (1.0f / (float)kB));
      atomicAdd(&out[1], lcp * (1.0f / (float)kB));
    }
  }
}

} // namespace

extern "C" void kernel_launch(void* const* d_in, const int* in_sizes, int n_in,
                              void* d_out, int out_size, void* d_ws, size_t ws_size,
                              hipStream_t stream) {
  (void)in_sizes; (void)n_in; (void)ws_size; (void)out_size;

  const float* dw  = (const float*)d_in[0];
  const float* X0  = (const float*)d_in[1];
  const float* A   = (const float*)d_in[2];
  const float* Bm  = (const float*)d_in[3];
  const float* Cm  = (const float*)d_in[4];
  const float* Dm  = (const float*)d_in[5];
  const float* pW1 = (const float*)d_in[6];
  const float* pb1 = (const float*)d_in[7];
  const float* pW2 = (const float*)d_in[8];
  const float* pb2 = (const float*)d_in[9];
  const float* pW3 = (const float*)d_in[10];
  const float* pb3 = (const float*)d_in[11];
  const float* zW1 = (const float*)d_in[12];
  const float* zb1 = (const float*)d_in[13];
  const float* zW2 = (const float*)d_in[14];
  const float* zb2 = (const float*)d_in[15];
  const float* zW3 = (const float*)d_in[16];
  const float* zb3 = (const float*)d_in[17];
  const float* yW1 = (const float*)d_in[18];
  const float* yb1 = (const float*)d_in[19];
  const float* yW2 = (const float*)d_in[20];
  const float* yb2 = (const float*)d_in[21];
  const float* yW3 = (const float*)d_in[22];
  const float* yb3 = (const float*)d_in[23];
  float* out = (float*)d_out;
  unsigned int* ws = (unsigned int*)d_ws;

  (void)hipMemsetAsync(out, 0, 2 * sizeof(float), stream);

  prep_kernel<<<kNFrag + 1, 64, 0, stream>>>(
      A, Bm, Cm, Dm,
      pW1, pb1, pW2, pb2, pW3, pb3,
      zW1, zb1, zW2, zb2, zW3, zb3,
      yW1, yb1, yW2, yb2, yW3, yb3, ws);

  bsde_kernel<<<kB / 16, 128, 0, stream>>>(dw, X0, ws, out);
}